// Round 6
// baseline (946.313 us; speedup 1.0000x reference)
//
#include <hip/hip_runtime.h>

#define NMAT 2048
#define KATTR 64
#define CAP 128
#define NITER 10
#define NCHUNK 8
#define CW 256           // cols/chunk: bf16 slice = 2048*256*2B = 1 MB (fits XCD L2)
#define NRG (NMAT / 4)   // 512 rowgroups per chunk
// HW_REG_XCC_ID (id=20, offset 0, size 32) getreg immediate: (31<<11)|(0<<6)|20
#define XCC_GETREG_IMM 63508

typedef unsigned short ushort8v __attribute__((ext_vector_type(8)));
typedef unsigned short ushort4v __attribute__((ext_vector_type(4)));

__device__ __forceinline__ unsigned short f2bf(float f) {
  unsigned u = __float_as_uint(f);
  return (unsigned short)((u + 0x7fff + ((u >> 16) & 1)) >> 16);
}
__device__ __forceinline__ float bf2f(unsigned short b) {
  return __uint_as_float((unsigned)b << 16);
}
// swizzled LDS dword index for 4-row interleaved T1 tile (proven R4/R5)
__device__ __forceinline__ int swz(int c) { return 4 * c + (((c >> 3) & 7) << 2); }

// --------------------------------------------------------------------------
// Build padded adjacency (ELL) for pattern(A); B == (A!=0), symmetric.
// --------------------------------------------------------------------------
__global__ __launch_bounds__(256) void k_build(
    const float* __restrict__ A, unsigned short* __restrict__ idx,
    unsigned short* __restrict__ idxT, int* __restrict__ cnt) {
  __shared__ int lcnt;
  int r = blockIdx.x;
  if (threadIdx.x == 0) lcnt = 0;
  __syncthreads();
  const float* row = A + (size_t)r * NMAT;
  for (int c = threadIdx.x; c < NMAT; c += 256) {
    if (row[c] != 0.0f) {
      int p = atomicAdd(&lcnt, 1);
      if (p < CAP) {
        idx[r * CAP + p] = (unsigned short)c;
        if (idxT) idxT[(size_t)p * NMAT + r] = (unsigned short)c;
      }
    }
  }
  __syncthreads();
  if (threadIdx.x == 0) cnt[r] = lcnt < CAP ? lcnt : CAP;
}

__global__ __launch_bounds__(256) void k_norm(const float* __restrict__ Nin,
                                              float* __restrict__ Nout) {
  int row = blockIdx.x * 4 + (threadIdx.x >> 6);
  int lane = threadIdx.x & 63;
  float v = Nin[(size_t)row * KATTR + lane];
  float ss = v * v;
#pragma unroll
  for (int o = 32; o > 0; o >>= 1) ss += __shfl_xor(ss, o);
  float nrm = sqrtf(ss);
  Nout[(size_t)row * KATTR + lane] = (nrm > 0.f) ? v / nrm : 0.f;
}

__global__ void k_gatherN(const unsigned short* __restrict__ idx,
                          const int* __restrict__ cnt,
                          const float* __restrict__ Nn,
                          float* __restrict__ C) {
  int i = blockIdx.x;
  int lane = threadIdx.x;  // blockDim = 64
  int nn = cnt[i];
  const unsigned short* ip = idx + i * CAP;
  float acc = 0.f;
  for (int t = 0; t < nn; ++t) {
    int k = ip[t];
    acc += Nn[(size_t)k * KATTR + lane];
  }
  C[(size_t)i * KATTR + lane] = acc;
}

__global__ __launch_bounds__(256) void k_transpose(const float* __restrict__ H,
                                                   float* __restrict__ Ht) {
  __shared__ float tile[64][65];
  int j0 = blockIdx.x * 64;
  int i0 = blockIdx.y * 64;
  int c = threadIdx.x & 63;
  int r0 = threadIdx.x >> 6;
  for (int r = r0; r < 64; r += 4)
    tile[r][c] = H[(size_t)(j0 + r) * NMAT + i0 + c];
  __syncthreads();
  for (int r = r0; r < 64; r += 4)
    Ht[(size_t)(i0 + r) * NMAT + j0 + c] = tile[c][r];
}

// --------------------------------------------------------------------------
// q = Nm>0&dm>0 ? Nm*rsqrt(Nm*dm) : 0.
// Also: M0gather = bf16(q*Ht) (iter-0 gather input), Q2 = alpha*q^2,
// M0base = bf16((1-alpha)*q*Ht) (additive base for M_new recurrence:
// M_new = q*s_new = (1-a)*q*Ht + a*q^2*S  since M0 = q*Ht).
// --------------------------------------------------------------------------
__global__ __launch_bounds__(256) void k_q(
    const float* __restrict__ N1n, const float* __restrict__ C1,
    const float* __restrict__ N2n, const float* __restrict__ C2,
    const float* __restrict__ Ht, float* __restrict__ q,
    float* __restrict__ Q2, unsigned short* __restrict__ M,
    unsigned short* __restrict__ M0base) {
  __shared__ float sA[64][68];
  __shared__ float sB[64][68];
  int i0 = blockIdx.y * 64, j0 = blockIdx.x * 64;
  int c = threadIdx.x & 63, r0 = threadIdx.x >> 6;
  int tx = threadIdx.x & 15, ty = threadIdx.x >> 4;
  const float alpha = 0.82f;

  float nmv[4][4] = {};
  float dmv[4][4] = {};

  for (int r = r0; r < 64; r += 4) {
    sA[c][r] = N1n[(size_t)(i0 + r) * KATTR + c];
    sB[c][r] = N2n[(size_t)(j0 + r) * KATTR + c];
  }
  __syncthreads();
#pragma unroll 4
  for (int k = 0; k < 64; ++k) {
    float4 a = *(const float4*)&sA[k][ty * 4];
    float4 b = *(const float4*)&sB[k][tx * 4];
    float av[4] = {a.x, a.y, a.z, a.w};
    float bv[4] = {b.x, b.y, b.z, b.w};
#pragma unroll
    for (int ii = 0; ii < 4; ++ii)
#pragma unroll
      for (int jj = 0; jj < 4; ++jj)
        nmv[ii][jj] = fmaf(av[ii], bv[jj], nmv[ii][jj]);
  }
  __syncthreads();
  for (int r = r0; r < 64; r += 4) {
    sA[c][r] = C1[(size_t)(i0 + r) * KATTR + c];
    sB[c][r] = C2[(size_t)(j0 + r) * KATTR + c];
  }
  __syncthreads();
#pragma unroll 4
  for (int k = 0; k < 64; ++k) {
    float4 a = *(const float4*)&sA[k][ty * 4];
    float4 b = *(const float4*)&sB[k][tx * 4];
    float av[4] = {a.x, a.y, a.z, a.w};
    float bv[4] = {b.x, b.y, b.z, b.w};
#pragma unroll
    for (int ii = 0; ii < 4; ++ii)
#pragma unroll
      for (int jj = 0; jj < 4; ++jj)
        dmv[ii][jj] = fmaf(av[ii], bv[jj], dmv[ii][jj]);
  }

#pragma unroll
  for (int ii = 0; ii < 4; ++ii) {
    int i = i0 + ty * 4 + ii;
    size_t base = (size_t)i * NMAT + j0 + tx * 4;
    float4 hv = *(const float4*)&Ht[base];
    float hvv[4] = {hv.x, hv.y, hv.z, hv.w};
    float qv[4], q2v[4];
    ushort4v mv, m0v;
#pragma unroll
    for (int jj = 0; jj < 4; ++jj) {
      float nmx = nmv[ii][jj];
      float D = nmx * dmv[ii][jj];
      float qq = (D > 0.f) ? nmx * rsqrtf(D) : 0.f;
      qv[jj] = qq;
      q2v[jj] = alpha * qq * qq;
      float m0 = qq * hvv[jj];
      mv[jj] = f2bf(m0);
      m0v[jj] = f2bf((1.0f - alpha) * m0);
    }
    *(float4*)&q[base] = make_float4(qv[0], qv[1], qv[2], qv[3]);
    *(float4*)&Q2[base] = make_float4(q2v[0], q2v[1], q2v[2], q2v[3]);
    *(ushort4v*)&M[base] = mv;
    *(ushort4v*)&M0base[base] = m0v;
  }
}

// --------------------------------------------------------------------------
// k1v: T1 = B1 @ M, exact-XCD column chunking.
// Block reads its physical XCD id (s_getreg HW_REG_XCC_ID, verified m09) and
// claims a (chunk==xcd, rowgroup) ticket from per-chunk atomic counters.
// Ring fallback if home chunk exhausted -> provably exactly-once coverage
// for any dispatch imbalance; garbage xcd id degrades to random placement,
// never incorrectness. All gathers from XCD c then hit the 1 MB (bf16)
// M[:, c*256..+255] slice resident in that XCD's 4 MB L2.
// --------------------------------------------------------------------------
__global__ __launch_bounds__(256) void k1v(
    const unsigned short* __restrict__ idx1, const int* __restrict__ cnt1,
    const unsigned short* __restrict__ Min, const float* __restrict__ MinF,
    float* __restrict__ T1, int* __restrict__ ctr, int in32) {
  __shared__ int s_c, s_rg;
  if (threadIdx.x == 0) {
    int xcc = __builtin_amdgcn_s_getreg(XCC_GETREG_IMM) & (NCHUNK - 1);
#pragma unroll
    for (int r = 0; r < NCHUNK; ++r) {
      int c = (xcc + r) & (NCHUNK - 1);
      int item = atomicAdd(&ctr[c], 1);
      if (item < NRG) {
        s_c = c;
        s_rg = item;
        break;
      }
    }
  }
  __syncthreads();
  int c = s_c, rg = s_rg;
  int w = threadIdx.x >> 6, lane = threadIdx.x & 63;
  int i = rg * 4 + w;
  int nn = cnt1[i];
  const unsigned short* ip = idx1 + i * CAP;
  size_t coff = (size_t)c * CW + (size_t)lane * 4;
  float a0 = 0.f, a1 = 0.f, a2 = 0.f, a3 = 0.f;
  float b0 = 0.f, b1 = 0.f, b2 = 0.f, b3 = 0.f;
  if (in32) {
    int t = 0;
    for (; t + 4 <= nn; t += 4) {
      uint2 pk = *(const uint2*)(ip + t);
      int k0 = pk.x & 0xffff, k1 = pk.x >> 16;
      int k2 = pk.y & 0xffff, k3 = pk.y >> 16;
      float4 v0 = *(const float4*)(MinF + (size_t)k0 * NMAT + coff);
      float4 v1 = *(const float4*)(MinF + (size_t)k1 * NMAT + coff);
      float4 v2 = *(const float4*)(MinF + (size_t)k2 * NMAT + coff);
      float4 v3 = *(const float4*)(MinF + (size_t)k3 * NMAT + coff);
      a0 += v0.x + v1.x; a1 += v0.y + v1.y;
      a2 += v0.z + v1.z; a3 += v0.w + v1.w;
      b0 += v2.x + v3.x; b1 += v2.y + v3.y;
      b2 += v2.z + v3.z; b3 += v2.w + v3.w;
    }
    for (; t < nn; ++t) {
      float4 v0 = *(const float4*)(MinF + (size_t)ip[t] * NMAT + coff);
      a0 += v0.x; a1 += v0.y; a2 += v0.z; a3 += v0.w;
    }
  } else {
    int t = 0;
    for (; t + 8 <= nn; t += 8) {
      uint4 pk = *(const uint4*)(ip + t);  // 16B-aligned (t%8==0, CAP=128)
      int k0 = pk.x & 0xffff, k1 = pk.x >> 16;
      int k2 = pk.y & 0xffff, k3 = pk.y >> 16;
      int k4 = pk.z & 0xffff, k5 = pk.z >> 16;
      int k6 = pk.w & 0xffff, k7 = pk.w >> 16;
      ushort4v v0 = *(const ushort4v*)(Min + (size_t)k0 * NMAT + coff);
      ushort4v v1 = *(const ushort4v*)(Min + (size_t)k1 * NMAT + coff);
      ushort4v v2 = *(const ushort4v*)(Min + (size_t)k2 * NMAT + coff);
      ushort4v v3 = *(const ushort4v*)(Min + (size_t)k3 * NMAT + coff);
      ushort4v v4 = *(const ushort4v*)(Min + (size_t)k4 * NMAT + coff);
      ushort4v v5 = *(const ushort4v*)(Min + (size_t)k5 * NMAT + coff);
      ushort4v v6 = *(const ushort4v*)(Min + (size_t)k6 * NMAT + coff);
      ushort4v v7 = *(const ushort4v*)(Min + (size_t)k7 * NMAT + coff);
      a0 += bf2f(v0[0]) + bf2f(v1[0]) + bf2f(v2[0]) + bf2f(v3[0]);
      a1 += bf2f(v0[1]) + bf2f(v1[1]) + bf2f(v2[1]) + bf2f(v3[1]);
      a2 += bf2f(v0[2]) + bf2f(v1[2]) + bf2f(v2[2]) + bf2f(v3[2]);
      a3 += bf2f(v0[3]) + bf2f(v1[3]) + bf2f(v2[3]) + bf2f(v3[3]);
      b0 += bf2f(v4[0]) + bf2f(v5[0]) + bf2f(v6[0]) + bf2f(v7[0]);
      b1 += bf2f(v4[1]) + bf2f(v5[1]) + bf2f(v6[1]) + bf2f(v7[1]);
      b2 += bf2f(v4[2]) + bf2f(v5[2]) + bf2f(v6[2]) + bf2f(v7[2]);
      b3 += bf2f(v4[3]) + bf2f(v5[3]) + bf2f(v6[3]) + bf2f(v7[3]);
    }
    for (; t + 4 <= nn; t += 4) {
      uint2 pk = *(const uint2*)(ip + t);
      int k0 = pk.x & 0xffff, k1 = pk.x >> 16;
      int k2 = pk.y & 0xffff, k3 = pk.y >> 16;
      ushort4v v0 = *(const ushort4v*)(Min + (size_t)k0 * NMAT + coff);
      ushort4v v1 = *(const ushort4v*)(Min + (size_t)k1 * NMAT + coff);
      ushort4v v2 = *(const ushort4v*)(Min + (size_t)k2 * NMAT + coff);
      ushort4v v3 = *(const ushort4v*)(Min + (size_t)k3 * NMAT + coff);
      a0 += bf2f(v0[0]) + bf2f(v1[0]) + bf2f(v2[0]) + bf2f(v3[0]);
      a1 += bf2f(v0[1]) + bf2f(v1[1]) + bf2f(v2[1]) + bf2f(v3[1]);
      a2 += bf2f(v0[2]) + bf2f(v1[2]) + bf2f(v2[2]) + bf2f(v3[2]);
      a3 += bf2f(v0[3]) + bf2f(v1[3]) + bf2f(v2[3]) + bf2f(v3[3]);
    }
    for (; t < nn; ++t) {
      ushort4v v0 = *(const ushort4v*)(Min + (size_t)ip[t] * NMAT + coff);
      a0 += bf2f(v0[0]); a1 += bf2f(v0[1]);
      a2 += bf2f(v0[2]); a3 += bf2f(v0[3]);
    }
  }
  a0 += b0; a1 += b1; a2 += b2; a3 += b3;
  *(float4*)(T1 + (size_t)i * NMAT + coff) = make_float4(a0, a1, a2, a3);
}

// --------------------------------------------------------------------------
// k2v: S = T1 @ B2^T via swizzled-interleaved LDS (one ds_read_b128/edge).
// Iters 0..8: M_new = (1-a)*M0 + a*q^2*S = fma(Q2, S, M0base)  [bf16/fp32].
// Iter 9:     s_out = (1-a)*Ht + a*q*S  (reads q, Ht only here).
// Grid 1024: block = (rowgroup, j-half) -> 16 waves/CU.
// --------------------------------------------------------------------------
__global__ __launch_bounds__(256) void k2v(
    const unsigned short* __restrict__ idx2T, const int* __restrict__ cnt2,
    const float* __restrict__ T1, const float* __restrict__ Q2,
    const unsigned short* __restrict__ M0base, const float* __restrict__ q,
    const float* __restrict__ Ht, unsigned short* __restrict__ Mout,
    float* __restrict__ MoutF, float* __restrict__ sout, int out32,
    int last) {
  __shared__ float lds[4 * NMAT + 32];
  int rg = blockIdx.x >> 1;
  int jh = blockIdx.x & 1;
  int i0 = rg * 4;
  int tid = threadIdx.x;
  int c0 = tid * 8;
  float4 ra[4], rb[4];
#pragma unroll
  for (int r = 0; r < 4; ++r) {
    const float* tr = T1 + (size_t)(i0 + r) * NMAT + c0;
    ra[r] = *(const float4*)tr;
    rb[r] = *(const float4*)(tr + 4);
  }
  *(float4*)&lds[swz(c0 + 0)] = make_float4(ra[0].x, ra[1].x, ra[2].x, ra[3].x);
  *(float4*)&lds[swz(c0 + 1)] = make_float4(ra[0].y, ra[1].y, ra[2].y, ra[3].y);
  *(float4*)&lds[swz(c0 + 2)] = make_float4(ra[0].z, ra[1].z, ra[2].z, ra[3].z);
  *(float4*)&lds[swz(c0 + 3)] = make_float4(ra[0].w, ra[1].w, ra[2].w, ra[3].w);
  *(float4*)&lds[swz(c0 + 4)] = make_float4(rb[0].x, rb[1].x, rb[2].x, rb[3].x);
  *(float4*)&lds[swz(c0 + 5)] = make_float4(rb[0].y, rb[1].y, rb[2].y, rb[3].y);
  *(float4*)&lds[swz(c0 + 6)] = make_float4(rb[0].z, rb[1].z, rb[2].z, rb[3].z);
  *(float4*)&lds[swz(c0 + 7)] = make_float4(rb[0].w, rb[1].w, rb[2].w, rb[3].w);
  __syncthreads();

  const float alpha = 0.82f;
  const float oma = 1.0f - alpha;
#pragma unroll
  for (int jj = 0; jj < 4; ++jj) {
    int j = jh * 1024 + jj * 256 + tid;
    int nn = cnt2[j];
    const unsigned short* ip = idx2T + j;
    float s0 = 0.f, s1 = 0.f, s2 = 0.f, s3 = 0.f;
    float u0 = 0.f, u1 = 0.f, u2 = 0.f, u3 = 0.f;
    int t = 0;
    for (; t + 2 <= nn; t += 2) {
      int ka = ip[(size_t)t * NMAT];
      int kb = ip[(size_t)(t + 1) * NMAT];
      float4 va = *(const float4*)&lds[swz(ka)];
      float4 vb = *(const float4*)&lds[swz(kb)];
      s0 += va.x; s1 += va.y; s2 += va.z; s3 += va.w;
      u0 += vb.x; u1 += vb.y; u2 += vb.z; u3 += vb.w;
    }
    if (t < nn) {
      int ka = ip[(size_t)t * NMAT];
      float4 va = *(const float4*)&lds[swz(ka)];
      s0 += va.x; s1 += va.y; s2 += va.z; s3 += va.w;
    }
    float sa[4] = {s0 + u0, s1 + u1, s2 + u2, s3 + u3};
    if (last) {
#pragma unroll
      for (int r = 0; r < 4; ++r) {
        size_t off = (size_t)(i0 + r) * NMAT + j;
        sout[off] = oma * Ht[off] + alpha * q[off] * sa[r];
      }
    } else if (out32) {
#pragma unroll
      for (int r = 0; r < 4; ++r) {
        size_t off = (size_t)(i0 + r) * NMAT + j;
        MoutF[off] = fmaf(Q2[off], sa[r], bf2f(M0base[off]));
      }
    } else {
#pragma unroll
      for (int r = 0; r < 4; ++r) {
        size_t off = (size_t)(i0 + r) * NMAT + j;
        Mout[off] = f2bf(fmaf(Q2[off], sa[r], bf2f(M0base[off])));
      }
    }
  }
}

extern "C" void kernel_launch(void* const* d_in, const int* in_sizes, int n_in,
                              void* d_out, int out_size, void* d_ws,
                              size_t ws_size, hipStream_t stream) {
  const float* A1 = (const float*)d_in[0];
  const float* A2 = (const float*)d_in[1];
  const float* N1 = (const float*)d_in[2];
  const float* N2 = (const float*)d_in[3];
  const float* H = (const float*)d_in[4];
  float* s_out = (float*)d_out;

  char* p = (char*)d_ws;
  auto take = [&](size_t bytes) {
    char* r = p;
    p += (bytes + 255) & ~(size_t)255;
    return r;
  };
  unsigned short* idx1 = (unsigned short*)take((size_t)NMAT * CAP * 2);
  unsigned short* idx2 = (unsigned short*)take((size_t)NMAT * CAP * 2);
  unsigned short* idx2T = (unsigned short*)take((size_t)CAP * NMAT * 2);
  int* cnt1 = (int*)take((size_t)NMAT * 4);
  int* cnt2 = (int*)take((size_t)NMAT * 4);
  int* ctrs = (int*)take((size_t)NITER * NCHUNK * 4);  // k1v ticket counters
  float* N1n = (float*)take((size_t)NMAT * KATTR * 4);
  float* N2n = (float*)take((size_t)NMAT * KATTR * 4);
  float* C1 = (float*)take((size_t)NMAT * KATTR * 4);
  float* C2 = (float*)take((size_t)NMAT * KATTR * 4);
  float* Ht = (float*)take((size_t)NMAT * NMAT * 4);
  float* q = (float*)take((size_t)NMAT * NMAT * 4);
  float* Q2 = (float*)take((size_t)NMAT * NMAT * 4);
  unsigned short* Mb0 = (unsigned short*)take((size_t)NMAT * NMAT * 2);
  unsigned short* Mb1 = (unsigned short*)take((size_t)NMAT * NMAT * 2);
  unsigned short* M0b = (unsigned short*)take((size_t)NMAT * NMAT * 2);
  float* Mf = (float*)take((size_t)NMAT * NMAT * 4);
  float* T1 = (float*)take((size_t)NMAT * NMAT * 4);
  if ((size_t)(p - (char*)d_ws) > ws_size) return;

  hipMemsetAsync(ctrs, 0, (size_t)NITER * NCHUNK * 4, stream);
  k_build<<<NMAT, 256, 0, stream>>>(A1, idx1, (unsigned short*)nullptr, cnt1);
  k_build<<<NMAT, 256, 0, stream>>>(A2, idx2, idx2T, cnt2);
  k_norm<<<NMAT / 4, 256, 0, stream>>>(N1, N1n);
  k_norm<<<NMAT / 4, 256, 0, stream>>>(N2, N2n);
  k_gatherN<<<NMAT, 64, 0, stream>>>(idx1, cnt1, N1n, C1);
  k_gatherN<<<NMAT, 64, 0, stream>>>(idx2, cnt2, N2n, C2);
  k_transpose<<<dim3(32, 32), 256, 0, stream>>>(H, Ht);
  k_q<<<dim3(32, 32), 256, 0, stream>>>(N1n, C1, N2n, C2, Ht, q, Q2, Mb0,
                                        M0b);
  for (int it = 0; it < NITER; ++it) {
    const unsigned short* Min = (it & 1) ? Mb1 : Mb0;
    unsigned short* Mout = (it & 1) ? Mb0 : Mb1;
    int in32 = (it == NITER - 1) ? 1 : 0;
    int out32 = (it == NITER - 2) ? 1 : 0;
    int last = (it == NITER - 1) ? 1 : 0;
    k1v<<<NCHUNK * NRG, 256, 0, stream>>>(idx1, cnt1, Min, Mf, T1,
                                          ctrs + it * NCHUNK, in32);
    k2v<<<2 * NRG, 256, 0, stream>>>(idx2T, cnt2, T1, Q2, M0b, q, Ht, Mout,
                                     Mf, s_out, out32, last);
  }
}

// Round 7
// 576.490 us; speedup vs baseline: 1.6415x; 1.6415x over previous
//
#include <hip/hip_runtime.h>

#define NMAT 2048
#define KATTR 64
#define CAP 128
#define NITER 10
#define NCHUNK 8
#define CW 256           // cols/chunk: bf16 slice = 2048*256*2B = 1 MB (fits XCD L2)
#define NRG (NMAT / 4)   // 512 rowgroups
// HW_REG_XCC_ID (id=20, offset 0, size 32) getreg immediate: (31<<11)|(0<<6)|20
#define XCC_GETREG_IMM 63508

typedef unsigned short ushort8v __attribute__((ext_vector_type(8)));
typedef unsigned short ushort4v __attribute__((ext_vector_type(4)));

__device__ __forceinline__ unsigned short f2bf(float f) {
  unsigned u = __float_as_uint(f);
  return (unsigned short)((u + 0x7fff + ((u >> 16) & 1)) >> 16);
}
__device__ __forceinline__ float bf2f(unsigned short b) {
  return __uint_as_float((unsigned)b << 16);
}
// swizzled LDS dword index for 4-row interleaved T1 tile (proven R4/R5)
__device__ __forceinline__ int swz(int c) { return 4 * c + (((c >> 3) & 7) << 2); }

// --------------------------------------------------------------------------
// Build padded adjacency (ELL) for pattern(A); B == (A!=0), symmetric.
// --------------------------------------------------------------------------
__global__ __launch_bounds__(256) void k_build(
    const float* __restrict__ A, unsigned short* __restrict__ idx,
    unsigned short* __restrict__ idxT, int* __restrict__ cnt) {
  __shared__ int lcnt;
  int r = blockIdx.x;
  if (threadIdx.x == 0) lcnt = 0;
  __syncthreads();
  const float* row = A + (size_t)r * NMAT;
  for (int c = threadIdx.x; c < NMAT; c += 256) {
    if (row[c] != 0.0f) {
      int p = atomicAdd(&lcnt, 1);
      if (p < CAP) {
        idx[r * CAP + p] = (unsigned short)c;
        if (idxT) idxT[(size_t)p * NMAT + r] = (unsigned short)c;
      }
    }
  }
  __syncthreads();
  if (threadIdx.x == 0) cnt[r] = lcnt < CAP ? lcnt : CAP;
}

__global__ __launch_bounds__(256) void k_norm(const float* __restrict__ Nin,
                                              float* __restrict__ Nout) {
  int row = blockIdx.x * 4 + (threadIdx.x >> 6);
  int lane = threadIdx.x & 63;
  float v = Nin[(size_t)row * KATTR + lane];
  float ss = v * v;
#pragma unroll
  for (int o = 32; o > 0; o >>= 1) ss += __shfl_xor(ss, o);
  float nrm = sqrtf(ss);
  Nout[(size_t)row * KATTR + lane] = (nrm > 0.f) ? v / nrm : 0.f;
}

__global__ void k_gatherN(const unsigned short* __restrict__ idx,
                          const int* __restrict__ cnt,
                          const float* __restrict__ Nn,
                          float* __restrict__ C) {
  int i = blockIdx.x;
  int lane = threadIdx.x;  // blockDim = 64
  int nn = cnt[i];
  const unsigned short* ip = idx + i * CAP;
  float acc = 0.f;
  for (int t = 0; t < nn; ++t) {
    int k = ip[t];
    acc += Nn[(size_t)k * KATTR + lane];
  }
  C[(size_t)i * KATTR + lane] = acc;
}

__global__ __launch_bounds__(256) void k_transpose(const float* __restrict__ H,
                                                   float* __restrict__ Ht) {
  __shared__ float tile[64][65];
  int j0 = blockIdx.x * 64;
  int i0 = blockIdx.y * 64;
  int c = threadIdx.x & 63;
  int r0 = threadIdx.x >> 6;
  for (int r = r0; r < 64; r += 4)
    tile[r][c] = H[(size_t)(j0 + r) * NMAT + i0 + c];
  __syncthreads();
  for (int r = r0; r < 64; r += 4)
    Ht[(size_t)(i0 + r) * NMAT + j0 + c] = tile[c][r];
}

// --------------------------------------------------------------------------
// q = Nm>0&dm>0 ? Nm*rsqrt(Nm*dm) : 0.
// Also: M0gather = bf16(q*Ht), Q2 = alpha*q^2, M0base = bf16((1-a)*q*Ht)
// (M_new = q*s_new = (1-a)*q*Ht + a*q^2*S).
// --------------------------------------------------------------------------
__global__ __launch_bounds__(256) void k_q(
    const float* __restrict__ N1n, const float* __restrict__ C1,
    const float* __restrict__ N2n, const float* __restrict__ C2,
    const float* __restrict__ Ht, float* __restrict__ q,
    float* __restrict__ Q2, unsigned short* __restrict__ M,
    unsigned short* __restrict__ M0base) {
  __shared__ float sA[64][68];
  __shared__ float sB[64][68];
  int i0 = blockIdx.y * 64, j0 = blockIdx.x * 64;
  int c = threadIdx.x & 63, r0 = threadIdx.x >> 6;
  int tx = threadIdx.x & 15, ty = threadIdx.x >> 4;
  const float alpha = 0.82f;

  float nmv[4][4] = {};
  float dmv[4][4] = {};

  for (int r = r0; r < 64; r += 4) {
    sA[c][r] = N1n[(size_t)(i0 + r) * KATTR + c];
    sB[c][r] = N2n[(size_t)(j0 + r) * KATTR + c];
  }
  __syncthreads();
#pragma unroll 4
  for (int k = 0; k < 64; ++k) {
    float4 a = *(const float4*)&sA[k][ty * 4];
    float4 b = *(const float4*)&sB[k][tx * 4];
    float av[4] = {a.x, a.y, a.z, a.w};
    float bv[4] = {b.x, b.y, b.z, b.w};
#pragma unroll
    for (int ii = 0; ii < 4; ++ii)
#pragma unroll
      for (int jj = 0; jj < 4; ++jj)
        nmv[ii][jj] = fmaf(av[ii], bv[jj], nmv[ii][jj]);
  }
  __syncthreads();
  for (int r = r0; r < 64; r += 4) {
    sA[c][r] = C1[(size_t)(i0 + r) * KATTR + c];
    sB[c][r] = C2[(size_t)(j0 + r) * KATTR + c];
  }
  __syncthreads();
#pragma unroll 4
  for (int k = 0; k < 64; ++k) {
    float4 a = *(const float4*)&sA[k][ty * 4];
    float4 b = *(const float4*)&sB[k][tx * 4];
    float av[4] = {a.x, a.y, a.z, a.w};
    float bv[4] = {b.x, b.y, b.z, b.w};
#pragma unroll
    for (int ii = 0; ii < 4; ++ii)
#pragma unroll
      for (int jj = 0; jj < 4; ++jj)
        dmv[ii][jj] = fmaf(av[ii], bv[jj], dmv[ii][jj]);
  }

#pragma unroll
  for (int ii = 0; ii < 4; ++ii) {
    int i = i0 + ty * 4 + ii;
    size_t base = (size_t)i * NMAT + j0 + tx * 4;
    float4 hv = *(const float4*)&Ht[base];
    float hvv[4] = {hv.x, hv.y, hv.z, hv.w};
    float qv[4], q2v[4];
    ushort4v mv, m0v;
#pragma unroll
    for (int jj = 0; jj < 4; ++jj) {
      float nmx = nmv[ii][jj];
      float D = nmx * dmv[ii][jj];
      float qq = (D > 0.f) ? nmx * rsqrtf(D) : 0.f;
      qv[jj] = qq;
      q2v[jj] = alpha * qq * qq;
      float m0 = qq * hvv[jj];
      mv[jj] = f2bf(m0);
      m0v[jj] = f2bf((1.0f - alpha) * m0);
    }
    *(float4*)&q[base] = make_float4(qv[0], qv[1], qv[2], qv[3]);
    *(float4*)&Q2[base] = make_float4(q2v[0], q2v[1], q2v[2], q2v[3]);
    *(ushort4v*)&M[base] = mv;
    *(ushort4v*)&M0base[base] = m0v;
  }
}

// --------------------------------------------------------------------------
// k1v: T1 = B1 @ M, exact-XCD column chunking, LOW-CONTENTION assignment.
// rg = blockIdx>>3 (static). The 8 blocks sharing rg claim distinct chunks
// via atomicOr(&mask[rg], 1<<c), ring-ordered starting from the block's
// physical XCD id (s_getreg HW_REG_XCC_ID). atomicOr's returned old value
// makes claims exactly-once; pigeonhole (8 blocks, 8 bits, failed bit stays
// owned) bounds attempts at 8. Round-robin dispatch -> first try succeeds
// and all gathers stay XCD-local; any other dispatch only degrades locality.
// R6 evidence: this residency collapses FETCH 121->9 MB; R6's cost was
// 512-way ticket-counter contention, which this removes.
// --------------------------------------------------------------------------
__global__ __launch_bounds__(256) void k1v(
    const unsigned short* __restrict__ idx1, const int* __restrict__ cnt1,
    const unsigned short* __restrict__ Min, const float* __restrict__ MinF,
    float* __restrict__ T1, int* __restrict__ mask, int in32) {
  __shared__ int s_c;
  int rg = blockIdx.x >> 3;
  if (threadIdx.x == 0) {
    int xcc = __builtin_amdgcn_s_getreg(XCC_GETREG_IMM) & (NCHUNK - 1);
    int got = xcc;
#pragma unroll
    for (int r = 0; r < NCHUNK; ++r) {
      int c = (xcc + r) & (NCHUNK - 1);
      int old = atomicOr(&mask[rg], 1 << c);
      if (((old >> c) & 1) == 0) {
        got = c;
        break;
      }
    }
    s_c = got;
  }
  __syncthreads();
  int c = s_c;
  int w = threadIdx.x >> 6, lane = threadIdx.x & 63;
  int i = rg * 4 + w;
  int nn = cnt1[i];
  const unsigned short* ip = idx1 + i * CAP;
  size_t coff = (size_t)c * CW + (size_t)lane * 4;
  float a0 = 0.f, a1 = 0.f, a2 = 0.f, a3 = 0.f;
  float b0 = 0.f, b1 = 0.f, b2 = 0.f, b3 = 0.f;
  if (in32) {
    int t = 0;
    for (; t + 4 <= nn; t += 4) {
      uint2 pk = *(const uint2*)(ip + t);
      int k0 = pk.x & 0xffff, k1 = pk.x >> 16;
      int k2 = pk.y & 0xffff, k3 = pk.y >> 16;
      float4 v0 = *(const float4*)(MinF + (size_t)k0 * NMAT + coff);
      float4 v1 = *(const float4*)(MinF + (size_t)k1 * NMAT + coff);
      float4 v2 = *(const float4*)(MinF + (size_t)k2 * NMAT + coff);
      float4 v3 = *(const float4*)(MinF + (size_t)k3 * NMAT + coff);
      a0 += v0.x + v1.x; a1 += v0.y + v1.y;
      a2 += v0.z + v1.z; a3 += v0.w + v1.w;
      b0 += v2.x + v3.x; b1 += v2.y + v3.y;
      b2 += v2.z + v3.z; b3 += v2.w + v3.w;
    }
    for (; t < nn; ++t) {
      float4 v0 = *(const float4*)(MinF + (size_t)ip[t] * NMAT + coff);
      a0 += v0.x; a1 += v0.y; a2 += v0.z; a3 += v0.w;
    }
  } else {
    int t = 0;
    for (; t + 8 <= nn; t += 8) {
      uint4 pk = *(const uint4*)(ip + t);  // 16B-aligned (t%8==0, CAP=128)
      int k0 = pk.x & 0xffff, k1 = pk.x >> 16;
      int k2 = pk.y & 0xffff, k3 = pk.y >> 16;
      int k4 = pk.z & 0xffff, k5 = pk.z >> 16;
      int k6 = pk.w & 0xffff, k7 = pk.w >> 16;
      ushort4v v0 = *(const ushort4v*)(Min + (size_t)k0 * NMAT + coff);
      ushort4v v1 = *(const ushort4v*)(Min + (size_t)k1 * NMAT + coff);
      ushort4v v2 = *(const ushort4v*)(Min + (size_t)k2 * NMAT + coff);
      ushort4v v3 = *(const ushort4v*)(Min + (size_t)k3 * NMAT + coff);
      ushort4v v4 = *(const ushort4v*)(Min + (size_t)k4 * NMAT + coff);
      ushort4v v5 = *(const ushort4v*)(Min + (size_t)k5 * NMAT + coff);
      ushort4v v6 = *(const ushort4v*)(Min + (size_t)k6 * NMAT + coff);
      ushort4v v7 = *(const ushort4v*)(Min + (size_t)k7 * NMAT + coff);
      a0 += bf2f(v0[0]) + bf2f(v1[0]) + bf2f(v2[0]) + bf2f(v3[0]);
      a1 += bf2f(v0[1]) + bf2f(v1[1]) + bf2f(v2[1]) + bf2f(v3[1]);
      a2 += bf2f(v0[2]) + bf2f(v1[2]) + bf2f(v2[2]) + bf2f(v3[2]);
      a3 += bf2f(v0[3]) + bf2f(v1[3]) + bf2f(v2[3]) + bf2f(v3[3]);
      b0 += bf2f(v4[0]) + bf2f(v5[0]) + bf2f(v6[0]) + bf2f(v7[0]);
      b1 += bf2f(v4[1]) + bf2f(v5[1]) + bf2f(v6[1]) + bf2f(v7[1]);
      b2 += bf2f(v4[2]) + bf2f(v5[2]) + bf2f(v6[2]) + bf2f(v7[2]);
      b3 += bf2f(v4[3]) + bf2f(v5[3]) + bf2f(v6[3]) + bf2f(v7[3]);
    }
    for (; t + 4 <= nn; t += 4) {
      uint2 pk = *(const uint2*)(ip + t);
      int k0 = pk.x & 0xffff, k1 = pk.x >> 16;
      int k2 = pk.y & 0xffff, k3 = pk.y >> 16;
      ushort4v v0 = *(const ushort4v*)(Min + (size_t)k0 * NMAT + coff);
      ushort4v v1 = *(const ushort4v*)(Min + (size_t)k1 * NMAT + coff);
      ushort4v v2 = *(const ushort4v*)(Min + (size_t)k2 * NMAT + coff);
      ushort4v v3 = *(const ushort4v*)(Min + (size_t)k3 * NMAT + coff);
      a0 += bf2f(v0[0]) + bf2f(v1[0]) + bf2f(v2[0]) + bf2f(v3[0]);
      a1 += bf2f(v0[1]) + bf2f(v1[1]) + bf2f(v2[1]) + bf2f(v3[1]);
      a2 += bf2f(v0[2]) + bf2f(v1[2]) + bf2f(v2[2]) + bf2f(v3[2]);
      a3 += bf2f(v0[3]) + bf2f(v1[3]) + bf2f(v2[3]) + bf2f(v3[3]);
    }
    for (; t < nn; ++t) {
      ushort4v v0 = *(const ushort4v*)(Min + (size_t)ip[t] * NMAT + coff);
      a0 += bf2f(v0[0]); a1 += bf2f(v0[1]);
      a2 += bf2f(v0[2]); a3 += bf2f(v0[3]);
    }
  }
  a0 += b0; a1 += b1; a2 += b2; a3 += b3;
  *(float4*)(T1 + (size_t)i * NMAT + coff) = make_float4(a0, a1, a2, a3);
}

// --------------------------------------------------------------------------
// k2v: S = T1 @ B2^T via swizzled-interleaved LDS (one ds_read_b128/edge).
// Iters 0..8: M_new = fma(Q2, S, M0base) [bf16/fp32]; iter 9: s_out.
// Grid 1024: block = (rowgroup, j-half).
// --------------------------------------------------------------------------
__global__ __launch_bounds__(256) void k2v(
    const unsigned short* __restrict__ idx2T, const int* __restrict__ cnt2,
    const float* __restrict__ T1, const float* __restrict__ Q2,
    const unsigned short* __restrict__ M0base, const float* __restrict__ q,
    const float* __restrict__ Ht, unsigned short* __restrict__ Mout,
    float* __restrict__ MoutF, float* __restrict__ sout, int out32,
    int last) {
  __shared__ float lds[4 * NMAT + 32];
  int rg = blockIdx.x >> 1;
  int jh = blockIdx.x & 1;
  int i0 = rg * 4;
  int tid = threadIdx.x;
  int c0 = tid * 8;
  float4 ra[4], rb[4];
#pragma unroll
  for (int r = 0; r < 4; ++r) {
    const float* tr = T1 + (size_t)(i0 + r) * NMAT + c0;
    ra[r] = *(const float4*)tr;
    rb[r] = *(const float4*)(tr + 4);
  }
  *(float4*)&lds[swz(c0 + 0)] = make_float4(ra[0].x, ra[1].x, ra[2].x, ra[3].x);
  *(float4*)&lds[swz(c0 + 1)] = make_float4(ra[0].y, ra[1].y, ra[2].y, ra[3].y);
  *(float4*)&lds[swz(c0 + 2)] = make_float4(ra[0].z, ra[1].z, ra[2].z, ra[3].z);
  *(float4*)&lds[swz(c0 + 3)] = make_float4(ra[0].w, ra[1].w, ra[2].w, ra[3].w);
  *(float4*)&lds[swz(c0 + 4)] = make_float4(rb[0].x, rb[1].x, rb[2].x, rb[3].x);
  *(float4*)&lds[swz(c0 + 5)] = make_float4(rb[0].y, rb[1].y, rb[2].y, rb[3].y);
  *(float4*)&lds[swz(c0 + 6)] = make_float4(rb[0].z, rb[1].z, rb[2].z, rb[3].z);
  *(float4*)&lds[swz(c0 + 7)] = make_float4(rb[0].w, rb[1].w, rb[2].w, rb[3].w);
  __syncthreads();

  const float alpha = 0.82f;
  const float oma = 1.0f - alpha;
#pragma unroll
  for (int jj = 0; jj < 4; ++jj) {
    int j = jh * 1024 + jj * 256 + tid;
    int nn = cnt2[j];
    const unsigned short* ip = idx2T + j;
    float s0 = 0.f, s1 = 0.f, s2 = 0.f, s3 = 0.f;
    float u0 = 0.f, u1 = 0.f, u2 = 0.f, u3 = 0.f;
    int t = 0;
    for (; t + 2 <= nn; t += 2) {
      int ka = ip[(size_t)t * NMAT];
      int kb = ip[(size_t)(t + 1) * NMAT];
      float4 va = *(const float4*)&lds[swz(ka)];
      float4 vb = *(const float4*)&lds[swz(kb)];
      s0 += va.x; s1 += va.y; s2 += va.z; s3 += va.w;
      u0 += vb.x; u1 += vb.y; u2 += vb.z; u3 += vb.w;
    }
    if (t < nn) {
      int ka = ip[(size_t)t * NMAT];
      float4 va = *(const float4*)&lds[swz(ka)];
      s0 += va.x; s1 += va.y; s2 += va.z; s3 += va.w;
    }
    float sa[4] = {s0 + u0, s1 + u1, s2 + u2, s3 + u3};
    if (last) {
#pragma unroll
      for (int r = 0; r < 4; ++r) {
        size_t off = (size_t)(i0 + r) * NMAT + j;
        sout[off] = oma * Ht[off] + alpha * q[off] * sa[r];
      }
    } else if (out32) {
#pragma unroll
      for (int r = 0; r < 4; ++r) {
        size_t off = (size_t)(i0 + r) * NMAT + j;
        MoutF[off] = fmaf(Q2[off], sa[r], bf2f(M0base[off]));
      }
    } else {
#pragma unroll
      for (int r = 0; r < 4; ++r) {
        size_t off = (size_t)(i0 + r) * NMAT + j;
        Mout[off] = f2bf(fmaf(Q2[off], sa[r], bf2f(M0base[off])));
      }
    }
  }
}

extern "C" void kernel_launch(void* const* d_in, const int* in_sizes, int n_in,
                              void* d_out, int out_size, void* d_ws,
                              size_t ws_size, hipStream_t stream) {
  const float* A1 = (const float*)d_in[0];
  const float* A2 = (const float*)d_in[1];
  const float* N1 = (const float*)d_in[2];
  const float* N2 = (const float*)d_in[3];
  const float* H = (const float*)d_in[4];
  float* s_out = (float*)d_out;

  char* p = (char*)d_ws;
  auto take = [&](size_t bytes) {
    char* r = p;
    p += (bytes + 255) & ~(size_t)255;
    return r;
  };
  unsigned short* idx1 = (unsigned short*)take((size_t)NMAT * CAP * 2);
  unsigned short* idx2 = (unsigned short*)take((size_t)NMAT * CAP * 2);
  unsigned short* idx2T = (unsigned short*)take((size_t)CAP * NMAT * 2);
  int* cnt1 = (int*)take((size_t)NMAT * 4);
  int* cnt2 = (int*)take((size_t)NMAT * 4);
  int* masks = (int*)take((size_t)NITER * NRG * 4);  // k1v claim bitmasks
  float* N1n = (float*)take((size_t)NMAT * KATTR * 4);
  float* N2n = (float*)take((size_t)NMAT * KATTR * 4);
  float* C1 = (float*)take((size_t)NMAT * KATTR * 4);
  float* C2 = (float*)take((size_t)NMAT * KATTR * 4);
  float* Ht = (float*)take((size_t)NMAT * NMAT * 4);
  float* q = (float*)take((size_t)NMAT * NMAT * 4);
  float* Q2 = (float*)take((size_t)NMAT * NMAT * 4);
  unsigned short* Mb0 = (unsigned short*)take((size_t)NMAT * NMAT * 2);
  unsigned short* Mb1 = (unsigned short*)take((size_t)NMAT * NMAT * 2);
  unsigned short* M0b = (unsigned short*)take((size_t)NMAT * NMAT * 2);
  float* Mf = (float*)take((size_t)NMAT * NMAT * 4);
  float* T1 = (float*)take((size_t)NMAT * NMAT * 4);
  if ((size_t)(p - (char*)d_ws) > ws_size) return;

  hipMemsetAsync(masks, 0, (size_t)NITER * NRG * 4, stream);
  k_build<<<NMAT, 256, 0, stream>>>(A1, idx1, (unsigned short*)nullptr, cnt1);
  k_build<<<NMAT, 256, 0, stream>>>(A2, idx2, idx2T, cnt2);
  k_norm<<<NMAT / 4, 256, 0, stream>>>(N1, N1n);
  k_norm<<<NMAT / 4, 256, 0, stream>>>(N2, N2n);
  k_gatherN<<<NMAT, 64, 0, stream>>>(idx1, cnt1, N1n, C1);
  k_gatherN<<<NMAT, 64, 0, stream>>>(idx2, cnt2, N2n, C2);
  k_transpose<<<dim3(32, 32), 256, 0, stream>>>(H, Ht);
  k_q<<<dim3(32, 32), 256, 0, stream>>>(N1n, C1, N2n, C2, Ht, q, Q2, Mb0,
                                        M0b);
  for (int it = 0; it < NITER; ++it) {
    const unsigned short* Min = (it & 1) ? Mb1 : Mb0;
    unsigned short* Mout = (it & 1) ? Mb0 : Mb1;
    int in32 = (it == NITER - 1) ? 1 : 0;
    int out32 = (it == NITER - 2) ? 1 : 0;
    int last = (it == NITER - 1) ? 1 : 0;
    k1v<<<NCHUNK * NRG, 256, 0, stream>>>(idx1, cnt1, Min, Mf, T1,
                                          masks + it * NRG, in32);
    k2v<<<2 * NRG, 256, 0, stream>>>(idx2T, cnt2, T1, Q2, M0b, q, Ht, Mout,
                                     Mf, s_out, out32, last);
  }
}

// Round 8
// 513.016 us; speedup vs baseline: 1.8446x; 1.1237x over previous
//
#include <hip/hip_runtime.h>

#define NMAT 2048
#define KATTR 64
#define CAP 128
#define NITER 10

typedef unsigned short ushort4v __attribute__((ext_vector_type(4)));

__device__ __forceinline__ unsigned short f2bf(float f) {
  unsigned u = __float_as_uint(f);
  return (unsigned short)((u + 0x7fff + ((u >> 16) & 1)) >> 16);
}
__device__ __forceinline__ float bf2f(unsigned short b) {
  return __uint_as_float((unsigned)b << 16);
}
// swizzled LDS dword index for 4-row interleaved T1 tile (proven R4-R7):
// bank-balanced transposed b128 writes, ~uniform random b128 gathers.
__device__ __forceinline__ int swz(int c) { return 4 * c + (((c >> 3) & 7) << 2); }

// --------------------------------------------------------------------------
// Build padded adjacency (ELL) for pattern(A); B == (A!=0), symmetric.
// --------------------------------------------------------------------------
__global__ __launch_bounds__(256) void k_build(
    const float* __restrict__ A, unsigned short* __restrict__ idx,
    unsigned short* __restrict__ idxT, int* __restrict__ cnt) {
  __shared__ int lcnt;
  int r = blockIdx.x;
  if (threadIdx.x == 0) lcnt = 0;
  __syncthreads();
  const float* row = A + (size_t)r * NMAT;
  for (int c = threadIdx.x; c < NMAT; c += 256) {
    if (row[c] != 0.0f) {
      int p = atomicAdd(&lcnt, 1);
      if (p < CAP) {
        idx[r * CAP + p] = (unsigned short)c;
        if (idxT) idxT[(size_t)p * NMAT + r] = (unsigned short)c;
      }
    }
  }
  __syncthreads();
  if (threadIdx.x == 0) cnt[r] = lcnt < CAP ? lcnt : CAP;
}

__global__ __launch_bounds__(256) void k_norm(const float* __restrict__ Nin,
                                              float* __restrict__ Nout) {
  int row = blockIdx.x * 4 + (threadIdx.x >> 6);
  int lane = threadIdx.x & 63;
  float v = Nin[(size_t)row * KATTR + lane];
  float ss = v * v;
#pragma unroll
  for (int o = 32; o > 0; o >>= 1) ss += __shfl_xor(ss, o);
  float nrm = sqrtf(ss);
  Nout[(size_t)row * KATTR + lane] = (nrm > 0.f) ? v / nrm : 0.f;
}

__global__ void k_gatherN(const unsigned short* __restrict__ idx,
                          const int* __restrict__ cnt,
                          const float* __restrict__ Nn,
                          float* __restrict__ C) {
  int i = blockIdx.x;
  int lane = threadIdx.x;  // blockDim = 64
  int nn = cnt[i];
  const unsigned short* ip = idx + i * CAP;
  float acc = 0.f;
  for (int t = 0; t < nn; ++t) {
    int k = ip[t];
    acc += Nn[(size_t)k * KATTR + lane];
  }
  C[(size_t)i * KATTR + lane] = acc;
}

__global__ __launch_bounds__(256) void k_transpose(const float* __restrict__ H,
                                                   float* __restrict__ Ht) {
  __shared__ float tile[64][65];
  int j0 = blockIdx.x * 64;
  int i0 = blockIdx.y * 64;
  int c = threadIdx.x & 63;
  int r0 = threadIdx.x >> 6;
  for (int r = r0; r < 64; r += 4)
    tile[r][c] = H[(size_t)(j0 + r) * NMAT + i0 + c];
  __syncthreads();
  for (int r = r0; r < 64; r += 4)
    Ht[(size_t)(i0 + r) * NMAT + j0 + c] = tile[c][r];
}

// --------------------------------------------------------------------------
// q = Nm>0&dm>0 ? Nm*rsqrt(Nm*dm) : 0.
// Also: M0gather = bf16(q*Ht), Q2 = alpha*q^2, M0base = bf16((1-a)*q*Ht)
// (M_new = q*s_new = (1-a)*q*Ht + a*q^2*S).
// --------------------------------------------------------------------------
__global__ __launch_bounds__(256) void k_q(
    const float* __restrict__ N1n, const float* __restrict__ C1,
    const float* __restrict__ N2n, const float* __restrict__ C2,
    const float* __restrict__ Ht, float* __restrict__ q,
    float* __restrict__ Q2, unsigned short* __restrict__ M,
    unsigned short* __restrict__ M0base) {
  __shared__ float sA[64][68];
  __shared__ float sB[64][68];
  int i0 = blockIdx.y * 64, j0 = blockIdx.x * 64;
  int c = threadIdx.x & 63, r0 = threadIdx.x >> 6;
  int tx = threadIdx.x & 15, ty = threadIdx.x >> 4;
  const float alpha = 0.82f;

  float nmv[4][4] = {};
  float dmv[4][4] = {};

  for (int r = r0; r < 64; r += 4) {
    sA[c][r] = N1n[(size_t)(i0 + r) * KATTR + c];
    sB[c][r] = N2n[(size_t)(j0 + r) * KATTR + c];
  }
  __syncthreads();
#pragma unroll 4
  for (int k = 0; k < 64; ++k) {
    float4 a = *(const float4*)&sA[k][ty * 4];
    float4 b = *(const float4*)&sB[k][tx * 4];
    float av[4] = {a.x, a.y, a.z, a.w};
    float bv[4] = {b.x, b.y, b.z, b.w};
#pragma unroll
    for (int ii = 0; ii < 4; ++ii)
#pragma unroll
      for (int jj = 0; jj < 4; ++jj)
        nmv[ii][jj] = fmaf(av[ii], bv[jj], nmv[ii][jj]);
  }
  __syncthreads();
  for (int r = r0; r < 64; r += 4) {
    sA[c][r] = C1[(size_t)(i0 + r) * KATTR + c];
    sB[c][r] = C2[(size_t)(j0 + r) * KATTR + c];
  }
  __syncthreads();
#pragma unroll 4
  for (int k = 0; k < 64; ++k) {
    float4 a = *(const float4*)&sA[k][ty * 4];
    float4 b = *(const float4*)&sB[k][tx * 4];
    float av[4] = {a.x, a.y, a.z, a.w};
    float bv[4] = {b.x, b.y, b.z, b.w};
#pragma unroll
    for (int ii = 0; ii < 4; ++ii)
#pragma unroll
      for (int jj = 0; jj < 4; ++jj)
        dmv[ii][jj] = fmaf(av[ii], bv[jj], dmv[ii][jj]);
  }

#pragma unroll
  for (int ii = 0; ii < 4; ++ii) {
    int i = i0 + ty * 4 + ii;
    size_t base = (size_t)i * NMAT + j0 + tx * 4;
    float4 hv = *(const float4*)&Ht[base];
    float hvv[4] = {hv.x, hv.y, hv.z, hv.w};
    float qv[4], q2v[4];
    ushort4v mv, m0v;
#pragma unroll
    for (int jj = 0; jj < 4; ++jj) {
      float nmx = nmv[ii][jj];
      float D = nmx * dmv[ii][jj];
      float qq = (D > 0.f) ? nmx * rsqrtf(D) : 0.f;
      qv[jj] = qq;
      q2v[jj] = alpha * qq * qq;
      float m0 = qq * hvv[jj];
      mv[jj] = f2bf(m0);
      m0v[jj] = f2bf((1.0f - alpha) * m0);
    }
    *(float4*)&q[base] = make_float4(qv[0], qv[1], qv[2], qv[3]);
    *(float4*)&Q2[base] = make_float4(q2v[0], q2v[1], q2v[2], q2v[3]);
    *(ushort4v*)&M[base] = mv;
    *(ushort4v*)&M0base[base] = m0v;
  }
}

// --------------------------------------------------------------------------
// One full iteration, fused (v2). Grid 512 x 512 threads (8 waves/block,
// ~3 blocks/CU -> up to 24 waves/CU; fixes R4-fusion's 8-wave starvation).
// Phase A: T1[i0..i0+3, :] = sum_{k in adj1(i)} Min[k, :], thread covers 4
//          cols (bf16: 8B loads, 8-deep unroll = 8 loads in flight — the
//          pipeline depth R5's split k1v proved out; fp32 path: 4-deep).
//          Result -> swizzled interleaved LDS (b128, bank-balanced).
// Phase B: S[r][j] = sum_{k in adj2(j)} T1[r][k] via one ds_read_b128/edge;
//          epilogue M_new = fma(Q2, S, M0base) [bf16 | fp32] or s_out.
// T1 never touches global (saves 64 MB/iter incl. R7's double-staging);
// 10 dispatches instead of 20.
// --------------------------------------------------------------------------
__global__ __launch_bounds__(512) void k_iter(
    const unsigned short* __restrict__ idx1, const int* __restrict__ cnt1,
    const unsigned short* __restrict__ idx2T, const int* __restrict__ cnt2,
    const unsigned short* __restrict__ Min, const float* __restrict__ MinF,
    const float* __restrict__ Q2, const unsigned short* __restrict__ M0base,
    const float* __restrict__ q, const float* __restrict__ Ht,
    unsigned short* __restrict__ Mout, float* __restrict__ MoutF,
    float* __restrict__ sout, int in32, int out32, int last) {
  __shared__ float lds[4 * NMAT + 32];
  int i0 = blockIdx.x * 4;
  int tid = threadIdx.x;  // 0..511
  int c0 = tid * 4;       // this thread's 4 columns

  // ---- Phase A: row gathers ----
  float acc[4][4];
#pragma unroll
  for (int r = 0; r < 4; ++r) {
    int nn = cnt1[i0 + r];
    const unsigned short* ip = idx1 + (i0 + r) * CAP;
    float a0 = 0.f, a1 = 0.f, a2 = 0.f, a3 = 0.f;
    float b0 = 0.f, b1 = 0.f, b2 = 0.f, b3 = 0.f;
    if (in32) {
      int t = 0;
      for (; t + 4 <= nn; t += 4) {
        uint2 pk = *(const uint2*)(ip + t);
        int k0 = pk.x & 0xffff, k1 = pk.x >> 16;
        int k2 = pk.y & 0xffff, k3 = pk.y >> 16;
        float4 v0 = *(const float4*)(MinF + (size_t)k0 * NMAT + c0);
        float4 v1 = *(const float4*)(MinF + (size_t)k1 * NMAT + c0);
        float4 v2 = *(const float4*)(MinF + (size_t)k2 * NMAT + c0);
        float4 v3 = *(const float4*)(MinF + (size_t)k3 * NMAT + c0);
        a0 += v0.x + v1.x; a1 += v0.y + v1.y;
        a2 += v0.z + v1.z; a3 += v0.w + v1.w;
        b0 += v2.x + v3.x; b1 += v2.y + v3.y;
        b2 += v2.z + v3.z; b3 += v2.w + v3.w;
      }
      for (; t < nn; ++t) {
        float4 v0 = *(const float4*)(MinF + (size_t)ip[t] * NMAT + c0);
        a0 += v0.x; a1 += v0.y; a2 += v0.z; a3 += v0.w;
      }
    } else {
      int t = 0;
      for (; t + 8 <= nn; t += 8) {
        uint4 pk = *(const uint4*)(ip + t);  // 16B-aligned (t%8==0, CAP=128)
        int k0 = pk.x & 0xffff, k1 = pk.x >> 16;
        int k2 = pk.y & 0xffff, k3 = pk.y >> 16;
        int k4 = pk.z & 0xffff, k5 = pk.z >> 16;
        int k6 = pk.w & 0xffff, k7 = pk.w >> 16;
        ushort4v v0 = *(const ushort4v*)(Min + (size_t)k0 * NMAT + c0);
        ushort4v v1 = *(const ushort4v*)(Min + (size_t)k1 * NMAT + c0);
        ushort4v v2 = *(const ushort4v*)(Min + (size_t)k2 * NMAT + c0);
        ushort4v v3 = *(const ushort4v*)(Min + (size_t)k3 * NMAT + c0);
        ushort4v v4 = *(const ushort4v*)(Min + (size_t)k4 * NMAT + c0);
        ushort4v v5 = *(const ushort4v*)(Min + (size_t)k5 * NMAT + c0);
        ushort4v v6 = *(const ushort4v*)(Min + (size_t)k6 * NMAT + c0);
        ushort4v v7 = *(const ushort4v*)(Min + (size_t)k7 * NMAT + c0);
        a0 += bf2f(v0[0]) + bf2f(v1[0]) + bf2f(v2[0]) + bf2f(v3[0]);
        a1 += bf2f(v0[1]) + bf2f(v1[1]) + bf2f(v2[1]) + bf2f(v3[1]);
        a2 += bf2f(v0[2]) + bf2f(v1[2]) + bf2f(v2[2]) + bf2f(v3[2]);
        a3 += bf2f(v0[3]) + bf2f(v1[3]) + bf2f(v2[3]) + bf2f(v3[3]);
        b0 += bf2f(v4[0]) + bf2f(v5[0]) + bf2f(v6[0]) + bf2f(v7[0]);
        b1 += bf2f(v4[1]) + bf2f(v5[1]) + bf2f(v6[1]) + bf2f(v7[1]);
        b2 += bf2f(v4[2]) + bf2f(v5[2]) + bf2f(v6[2]) + bf2f(v7[2]);
        b3 += bf2f(v4[3]) + bf2f(v5[3]) + bf2f(v6[3]) + bf2f(v7[3]);
      }
      for (; t + 4 <= nn; t += 4) {
        uint2 pk = *(const uint2*)(ip + t);
        int k0 = pk.x & 0xffff, k1 = pk.x >> 16;
        int k2 = pk.y & 0xffff, k3 = pk.y >> 16;
        ushort4v v0 = *(const ushort4v*)(Min + (size_t)k0 * NMAT + c0);
        ushort4v v1 = *(const ushort4v*)(Min + (size_t)k1 * NMAT + c0);
        ushort4v v2 = *(const ushort4v*)(Min + (size_t)k2 * NMAT + c0);
        ushort4v v3 = *(const ushort4v*)(Min + (size_t)k3 * NMAT + c0);
        a0 += bf2f(v0[0]) + bf2f(v1[0]) + bf2f(v2[0]) + bf2f(v3[0]);
        a1 += bf2f(v0[1]) + bf2f(v1[1]) + bf2f(v2[1]) + bf2f(v3[1]);
        a2 += bf2f(v0[2]) + bf2f(v1[2]) + bf2f(v2[2]) + bf2f(v3[2]);
        a3 += bf2f(v0[3]) + bf2f(v1[3]) + bf2f(v2[3]) + bf2f(v3[3]);
      }
      for (; t < nn; ++t) {
        ushort4v v0 = *(const ushort4v*)(Min + (size_t)ip[t] * NMAT + c0);
        a0 += bf2f(v0[0]); a1 += bf2f(v0[1]);
        a2 += bf2f(v0[2]); a3 += bf2f(v0[3]);
      }
    }
    a0 += b0; a1 += b1; a2 += b2; a3 += b3;
    acc[r][0] = a0; acc[r][1] = a1; acc[r][2] = a2; acc[r][3] = a3;
  }
#pragma unroll
  for (int cc = 0; cc < 4; ++cc) {
    *(float4*)&lds[swz(c0 + cc)] =
        make_float4(acc[0][cc], acc[1][cc], acc[2][cc], acc[3][cc]);
  }
  __syncthreads();

  // ---- Phase B: column gathers from LDS + epilogue ----
  const float alpha = 0.82f;
  const float oma = 1.0f - alpha;
#pragma unroll
  for (int jj = 0; jj < 4; ++jj) {
    int j = jj * 512 + tid;
    int nn = cnt2[j];
    const unsigned short* ip = idx2T + j;
    float s0 = 0.f, s1 = 0.f, s2 = 0.f, s3 = 0.f;
    float u0 = 0.f, u1 = 0.f, u2 = 0.f, u3 = 0.f;
    int t = 0;
    for (; t + 2 <= nn; t += 2) {
      int ka = ip[(size_t)t * NMAT];
      int kb = ip[(size_t)(t + 1) * NMAT];
      float4 va = *(const float4*)&lds[swz(ka)];
      float4 vb = *(const float4*)&lds[swz(kb)];
      s0 += va.x; s1 += va.y; s2 += va.z; s3 += va.w;
      u0 += vb.x; u1 += vb.y; u2 += vb.z; u3 += vb.w;
    }
    if (t < nn) {
      int ka = ip[(size_t)t * NMAT];
      float4 va = *(const float4*)&lds[swz(ka)];
      s0 += va.x; s1 += va.y; s2 += va.z; s3 += va.w;
    }
    float sa[4] = {s0 + u0, s1 + u1, s2 + u2, s3 + u3};
    if (last) {
#pragma unroll
      for (int r = 0; r < 4; ++r) {
        size_t off = (size_t)(i0 + r) * NMAT + j;
        sout[off] = oma * Ht[off] + alpha * q[off] * sa[r];
      }
    } else if (out32) {
#pragma unroll
      for (int r = 0; r < 4; ++r) {
        size_t off = (size_t)(i0 + r) * NMAT + j;
        MoutF[off] = fmaf(Q2[off], sa[r], bf2f(M0base[off]));
      }
    } else {
#pragma unroll
      for (int r = 0; r < 4; ++r) {
        size_t off = (size_t)(i0 + r) * NMAT + j;
        Mout[off] = f2bf(fmaf(Q2[off], sa[r], bf2f(M0base[off])));
      }
    }
  }
}

extern "C" void kernel_launch(void* const* d_in, const int* in_sizes, int n_in,
                              void* d_out, int out_size, void* d_ws,
                              size_t ws_size, hipStream_t stream) {
  const float* A1 = (const float*)d_in[0];
  const float* A2 = (const float*)d_in[1];
  const float* N1 = (const float*)d_in[2];
  const float* N2 = (const float*)d_in[3];
  const float* H = (const float*)d_in[4];
  float* s_out = (float*)d_out;

  char* p = (char*)d_ws;
  auto take = [&](size_t bytes) {
    char* r = p;
    p += (bytes + 255) & ~(size_t)255;
    return r;
  };
  unsigned short* idx1 = (unsigned short*)take((size_t)NMAT * CAP * 2);
  unsigned short* idx2 = (unsigned short*)take((size_t)NMAT * CAP * 2);
  unsigned short* idx2T = (unsigned short*)take((size_t)CAP * NMAT * 2);
  int* cnt1 = (int*)take((size_t)NMAT * 4);
  int* cnt2 = (int*)take((size_t)NMAT * 4);
  float* N1n = (float*)take((size_t)NMAT * KATTR * 4);
  float* N2n = (float*)take((size_t)NMAT * KATTR * 4);
  float* C1 = (float*)take((size_t)NMAT * KATTR * 4);
  float* C2 = (float*)take((size_t)NMAT * KATTR * 4);
  float* Ht = (float*)take((size_t)NMAT * NMAT * 4);
  float* q = (float*)take((size_t)NMAT * NMAT * 4);
  float* Q2 = (float*)take((size_t)NMAT * NMAT * 4);
  unsigned short* Mb0 = (unsigned short*)take((size_t)NMAT * NMAT * 2);
  unsigned short* Mb1 = (unsigned short*)take((size_t)NMAT * NMAT * 2);
  unsigned short* M0b = (unsigned short*)take((size_t)NMAT * NMAT * 2);
  float* Mf = (float*)take((size_t)NMAT * NMAT * 4);
  if ((size_t)(p - (char*)d_ws) > ws_size) return;

  k_build<<<NMAT, 256, 0, stream>>>(A1, idx1, (unsigned short*)nullptr, cnt1);
  k_build<<<NMAT, 256, 0, stream>>>(A2, idx2, idx2T, cnt2);
  k_norm<<<NMAT / 4, 256, 0, stream>>>(N1, N1n);
  k_norm<<<NMAT / 4, 256, 0, stream>>>(N2, N2n);
  k_gatherN<<<NMAT, 64, 0, stream>>>(idx1, cnt1, N1n, C1);
  k_gatherN<<<NMAT, 64, 0, stream>>>(idx2, cnt2, N2n, C2);
  k_transpose<<<dim3(32, 32), 256, 0, stream>>>(H, Ht);
  k_q<<<dim3(32, 32), 256, 0, stream>>>(N1n, C1, N2n, C2, Ht, q, Q2, Mb0,
                                        M0b);
  for (int it = 0; it < NITER; ++it) {
    const unsigned short* Min = (it & 1) ? Mb1 : Mb0;
    unsigned short* Mout = (it & 1) ? Mb0 : Mb1;
    int in32 = (it == NITER - 1) ? 1 : 0;
    int out32 = (it == NITER - 2) ? 1 : 0;
    int last = (it == NITER - 1) ? 1 : 0;
    k_iter<<<NMAT / 4, 512, 0, stream>>>(idx1, cnt1, idx2T, cnt2, Min, Mf,
                                         Q2, M0b, q, Ht, Mout, Mf, s_out,
                                         in32, out32, last);
  }
}

// Round 9
// 458.339 us; speedup vs baseline: 2.0647x; 1.1193x over previous
//
#include <hip/hip_runtime.h>

#define NMAT 2048
#define KATTR 64
#define CAP 128
#define NITER 10

typedef unsigned short ushort4v __attribute__((ext_vector_type(4)));

__device__ __forceinline__ unsigned short f2bf(float f) {
  unsigned u = __float_as_uint(f);
  return (unsigned short)((u + 0x7fff + ((u >> 16) & 1)) >> 16);
}
__device__ __forceinline__ float bf2f(unsigned short b) {
  return __uint_as_float((unsigned)b << 16);
}
// bf16 pair in one uint (little-endian: low half = even col)
__device__ __forceinline__ float bflo(unsigned v) {
  return __uint_as_float(v << 16);
}
__device__ __forceinline__ float bfhi(unsigned v) {
  return __uint_as_float(v & 0xffff0000u);
}
// swizzled LDS dword index for 4-row interleaved T1 tile (proven R4-R8):
// bank-balanced transposed b128 writes, ~uniform random b128 gathers.
__device__ __forceinline__ int swz(int c) { return 4 * c + (((c >> 3) & 7) << 2); }

// --------------------------------------------------------------------------
// Build padded adjacency (ELL) for pattern(A); B == (A!=0), symmetric.
// --------------------------------------------------------------------------
__global__ __launch_bounds__(256) void k_build(
    const float* __restrict__ A, unsigned short* __restrict__ idx,
    unsigned short* __restrict__ idxT, int* __restrict__ cnt) {
  __shared__ int lcnt;
  int r = blockIdx.x;
  if (threadIdx.x == 0) lcnt = 0;
  __syncthreads();
  const float* row = A + (size_t)r * NMAT;
  for (int c = threadIdx.x; c < NMAT; c += 256) {
    if (row[c] != 0.0f) {
      int p = atomicAdd(&lcnt, 1);
      if (p < CAP) {
        idx[r * CAP + p] = (unsigned short)c;
        if (idxT) idxT[(size_t)p * NMAT + r] = (unsigned short)c;
      }
    }
  }
  __syncthreads();
  if (threadIdx.x == 0) cnt[r] = lcnt < CAP ? lcnt : CAP;
}

__global__ __launch_bounds__(256) void k_norm(const float* __restrict__ Nin,
                                              float* __restrict__ Nout) {
  int row = blockIdx.x * 4 + (threadIdx.x >> 6);
  int lane = threadIdx.x & 63;
  float v = Nin[(size_t)row * KATTR + lane];
  float ss = v * v;
#pragma unroll
  for (int o = 32; o > 0; o >>= 1) ss += __shfl_xor(ss, o);
  float nrm = sqrtf(ss);
  Nout[(size_t)row * KATTR + lane] = (nrm > 0.f) ? v / nrm : 0.f;
}

__global__ void k_gatherN(const unsigned short* __restrict__ idx,
                          const int* __restrict__ cnt,
                          const float* __restrict__ Nn,
                          float* __restrict__ C) {
  int i = blockIdx.x;
  int lane = threadIdx.x;  // blockDim = 64
  int nn = cnt[i];
  const unsigned short* ip = idx + i * CAP;
  float acc = 0.f;
  for (int t = 0; t < nn; ++t) {
    int k = ip[t];
    acc += Nn[(size_t)k * KATTR + lane];
  }
  C[(size_t)i * KATTR + lane] = acc;
}

__global__ __launch_bounds__(256) void k_transpose(const float* __restrict__ H,
                                                   float* __restrict__ Ht) {
  __shared__ float tile[64][65];
  int j0 = blockIdx.x * 64;
  int i0 = blockIdx.y * 64;
  int c = threadIdx.x & 63;
  int r0 = threadIdx.x >> 6;
  for (int r = r0; r < 64; r += 4)
    tile[r][c] = H[(size_t)(j0 + r) * NMAT + i0 + c];
  __syncthreads();
  for (int r = r0; r < 64; r += 4)
    Ht[(size_t)(i0 + r) * NMAT + j0 + c] = tile[c][r];
}

// --------------------------------------------------------------------------
// q = Nm>0&dm>0 ? Nm*rsqrt(Nm*dm) : 0.
// Also: M0gather = bf16(q*Ht), Q2 = alpha*q^2, M0base = bf16((1-a)*q*Ht)
// (M_new = q*s_new = (1-a)*q*Ht + a*q^2*S).
// --------------------------------------------------------------------------
__global__ __launch_bounds__(256) void k_q(
    const float* __restrict__ N1n, const float* __restrict__ C1,
    const float* __restrict__ N2n, const float* __restrict__ C2,
    const float* __restrict__ Ht, float* __restrict__ q,
    float* __restrict__ Q2, unsigned short* __restrict__ M,
    unsigned short* __restrict__ M0base) {
  __shared__ float sA[64][68];
  __shared__ float sB[64][68];
  int i0 = blockIdx.y * 64, j0 = blockIdx.x * 64;
  int c = threadIdx.x & 63, r0 = threadIdx.x >> 6;
  int tx = threadIdx.x & 15, ty = threadIdx.x >> 4;
  const float alpha = 0.82f;

  float nmv[4][4] = {};
  float dmv[4][4] = {};

  for (int r = r0; r < 64; r += 4) {
    sA[c][r] = N1n[(size_t)(i0 + r) * KATTR + c];
    sB[c][r] = N2n[(size_t)(j0 + r) * KATTR + c];
  }
  __syncthreads();
#pragma unroll 4
  for (int k = 0; k < 64; ++k) {
    float4 a = *(const float4*)&sA[k][ty * 4];
    float4 b = *(const float4*)&sB[k][tx * 4];
    float av[4] = {a.x, a.y, a.z, a.w};
    float bv[4] = {b.x, b.y, b.z, b.w};
#pragma unroll
    for (int ii = 0; ii < 4; ++ii)
#pragma unroll
      for (int jj = 0; jj < 4; ++jj)
        nmv[ii][jj] = fmaf(av[ii], bv[jj], nmv[ii][jj]);
  }
  __syncthreads();
  for (int r = r0; r < 64; r += 4) {
    sA[c][r] = C1[(size_t)(i0 + r) * KATTR + c];
    sB[c][r] = C2[(size_t)(j0 + r) * KATTR + c];
  }
  __syncthreads();
#pragma unroll 4
  for (int k = 0; k < 64; ++k) {
    float4 a = *(const float4*)&sA[k][ty * 4];
    float4 b = *(const float4*)&sB[k][tx * 4];
    float av[4] = {a.x, a.y, a.z, a.w};
    float bv[4] = {b.x, b.y, b.z, b.w};
#pragma unroll
    for (int ii = 0; ii < 4; ++ii)
#pragma unroll
      for (int jj = 0; jj < 4; ++jj)
        dmv[ii][jj] = fmaf(av[ii], bv[jj], dmv[ii][jj]);
  }

#pragma unroll
  for (int ii = 0; ii < 4; ++ii) {
    int i = i0 + ty * 4 + ii;
    size_t base = (size_t)i * NMAT + j0 + tx * 4;
    float4 hv = *(const float4*)&Ht[base];
    float hvv[4] = {hv.x, hv.y, hv.z, hv.w};
    float qv[4], q2v[4];
    ushort4v mv, m0v;
#pragma unroll
    for (int jj = 0; jj < 4; ++jj) {
      float nmx = nmv[ii][jj];
      float D = nmx * dmv[ii][jj];
      float qq = (D > 0.f) ? nmx * rsqrtf(D) : 0.f;
      qv[jj] = qq;
      q2v[jj] = alpha * qq * qq;
      float m0 = qq * hvv[jj];
      mv[jj] = f2bf(m0);
      m0v[jj] = f2bf((1.0f - alpha) * m0);
    }
    *(float4*)&q[base] = make_float4(qv[0], qv[1], qv[2], qv[3]);
    *(float4*)&Q2[base] = make_float4(q2v[0], q2v[1], q2v[2], q2v[3]);
    *(ushort4v*)&M[base] = mv;
    *(ushort4v*)&M0base[base] = m0v;
  }
}

// --------------------------------------------------------------------------
// One full iteration, fused (v3). Grid 512 x 1024 threads (16 waves/block,
// 2 blocks/CU -> 32 waves/CU = HW max; R8's 512x512 capped at 16 waves/CU
// and measured latency-bound at 34% occupancy / 2.9 TB/s).
// Phase A: T1[i0..i0+3,:] = sum_{k in adj1(i)} Min[k,:]; thread owns 2 cols
//          (bf16 pair = one uint load, 2 VALU unpack; 8-deep pipeline).
// Phase B: S[r][j] = sum_{k in adj2(j)} T1[r][k] via one ds_read_b128/edge
//          (4-deep); epilogue fma(Q2,S,M0base) -> bf16/fp32 M, or s_out.
// --------------------------------------------------------------------------
__global__ __launch_bounds__(1024, 8) void k_iter(
    const unsigned short* __restrict__ idx1, const int* __restrict__ cnt1,
    const unsigned short* __restrict__ idx2T, const int* __restrict__ cnt2,
    const unsigned short* __restrict__ Min, const float* __restrict__ MinF,
    const float* __restrict__ Q2, const unsigned short* __restrict__ M0base,
    const float* __restrict__ q, const float* __restrict__ Ht,
    unsigned short* __restrict__ Mout, float* __restrict__ MoutF,
    float* __restrict__ sout, int in32, int out32, int last) {
  __shared__ float lds[4 * NMAT + 32];
  int i0 = blockIdx.x * 4;
  int tid = threadIdx.x;  // 0..1023
  int c0 = tid * 2;       // this thread's 2 columns

  // ---- Phase A: row gathers ----
  float acc[4][2];
#pragma unroll
  for (int r = 0; r < 4; ++r) {
    int nn = cnt1[i0 + r];
    const unsigned short* ip = idx1 + (i0 + r) * CAP;
    float a0 = 0.f, a1 = 0.f;  // col c0, c0+1
    float b0 = 0.f, b1 = 0.f;
    if (in32) {
      int t = 0;
      for (; t + 4 <= nn; t += 4) {
        uint2 pk = *(const uint2*)(ip + t);
        int k0 = pk.x & 0xffff, k1 = pk.x >> 16;
        int k2 = pk.y & 0xffff, k3 = pk.y >> 16;
        float2 v0 = *(const float2*)(MinF + (size_t)k0 * NMAT + c0);
        float2 v1 = *(const float2*)(MinF + (size_t)k1 * NMAT + c0);
        float2 v2 = *(const float2*)(MinF + (size_t)k2 * NMAT + c0);
        float2 v3 = *(const float2*)(MinF + (size_t)k3 * NMAT + c0);
        a0 += v0.x + v1.x; a1 += v0.y + v1.y;
        b0 += v2.x + v3.x; b1 += v2.y + v3.y;
      }
      for (; t < nn; ++t) {
        float2 v0 = *(const float2*)(MinF + (size_t)ip[t] * NMAT + c0);
        a0 += v0.x; a1 += v0.y;
      }
    } else {
      int t = 0;
      for (; t + 8 <= nn; t += 8) {
        uint4 pk = *(const uint4*)(ip + t);  // 16B-aligned (t%8==0, CAP=128)
        int k0 = pk.x & 0xffff, k1 = pk.x >> 16;
        int k2 = pk.y & 0xffff, k3 = pk.y >> 16;
        int k4 = pk.z & 0xffff, k5 = pk.z >> 16;
        int k6 = pk.w & 0xffff, k7 = pk.w >> 16;
        unsigned v0 = *(const unsigned*)(Min + (size_t)k0 * NMAT + c0);
        unsigned v1 = *(const unsigned*)(Min + (size_t)k1 * NMAT + c0);
        unsigned v2 = *(const unsigned*)(Min + (size_t)k2 * NMAT + c0);
        unsigned v3 = *(const unsigned*)(Min + (size_t)k3 * NMAT + c0);
        unsigned v4 = *(const unsigned*)(Min + (size_t)k4 * NMAT + c0);
        unsigned v5 = *(const unsigned*)(Min + (size_t)k5 * NMAT + c0);
        unsigned v6 = *(const unsigned*)(Min + (size_t)k6 * NMAT + c0);
        unsigned v7 = *(const unsigned*)(Min + (size_t)k7 * NMAT + c0);
        a0 += bflo(v0) + bflo(v1) + bflo(v2) + bflo(v3);
        a1 += bfhi(v0) + bfhi(v1) + bfhi(v2) + bfhi(v3);
        b0 += bflo(v4) + bflo(v5) + bflo(v6) + bflo(v7);
        b1 += bfhi(v4) + bfhi(v5) + bfhi(v6) + bfhi(v7);
      }
      for (; t + 4 <= nn; t += 4) {
        uint2 pk = *(const uint2*)(ip + t);
        int k0 = pk.x & 0xffff, k1 = pk.x >> 16;
        int k2 = pk.y & 0xffff, k3 = pk.y >> 16;
        unsigned v0 = *(const unsigned*)(Min + (size_t)k0 * NMAT + c0);
        unsigned v1 = *(const unsigned*)(Min + (size_t)k1 * NMAT + c0);
        unsigned v2 = *(const unsigned*)(Min + (size_t)k2 * NMAT + c0);
        unsigned v3 = *(const unsigned*)(Min + (size_t)k3 * NMAT + c0);
        a0 += bflo(v0) + bflo(v1) + bflo(v2) + bflo(v3);
        a1 += bfhi(v0) + bfhi(v1) + bfhi(v2) + bfhi(v3);
      }
      for (; t < nn; ++t) {
        unsigned v0 = *(const unsigned*)(Min + (size_t)ip[t] * NMAT + c0);
        a0 += bflo(v0); a1 += bfhi(v0);
      }
    }
    acc[r][0] = a0 + b0;
    acc[r][1] = a1 + b1;
  }
  *(float4*)&lds[swz(c0)] =
      make_float4(acc[0][0], acc[1][0], acc[2][0], acc[3][0]);
  *(float4*)&lds[swz(c0 + 1)] =
      make_float4(acc[0][1], acc[1][1], acc[2][1], acc[3][1]);
  __syncthreads();

  // ---- Phase B: column gathers from LDS + epilogue ----
  const float alpha = 0.82f;
  const float oma = 1.0f - alpha;
#pragma unroll
  for (int jj = 0; jj < 2; ++jj) {
    int j = jj * 1024 + tid;
    int nn = cnt2[j];
    const unsigned short* ip = idx2T + j;
    float s0 = 0.f, s1 = 0.f, s2 = 0.f, s3 = 0.f;
    float u0 = 0.f, u1 = 0.f, u2 = 0.f, u3 = 0.f;
    int t = 0;
    for (; t + 4 <= nn; t += 4) {
      int ka = ip[(size_t)t * NMAT];
      int kb = ip[(size_t)(t + 1) * NMAT];
      int kc = ip[(size_t)(t + 2) * NMAT];
      int kd = ip[(size_t)(t + 3) * NMAT];
      float4 va = *(const float4*)&lds[swz(ka)];
      float4 vb = *(const float4*)&lds[swz(kb)];
      float4 vc = *(const float4*)&lds[swz(kc)];
      float4 vd = *(const float4*)&lds[swz(kd)];
      s0 += va.x + vc.x; s1 += va.y + vc.y;
      s2 += va.z + vc.z; s3 += va.w + vc.w;
      u0 += vb.x + vd.x; u1 += vb.y + vd.y;
      u2 += vb.z + vd.z; u3 += vb.w + vd.w;
    }
    for (; t < nn; ++t) {
      int ka = ip[(size_t)t * NMAT];
      float4 va = *(const float4*)&lds[swz(ka)];
      s0 += va.x; s1 += va.y; s2 += va.z; s3 += va.w;
    }
    float sa[4] = {s0 + u0, s1 + u1, s2 + u2, s3 + u3};
    if (last) {
#pragma unroll
      for (int r = 0; r < 4; ++r) {
        size_t off = (size_t)(i0 + r) * NMAT + j;
        sout[off] = oma * Ht[off] + alpha * q[off] * sa[r];
      }
    } else if (out32) {
#pragma unroll
      for (int r = 0; r < 4; ++r) {
        size_t off = (size_t)(i0 + r) * NMAT + j;
        MoutF[off] = fmaf(Q2[off], sa[r], bf2f(M0base[off]));
      }
    } else {
#pragma unroll
      for (int r = 0; r < 4; ++r) {
        size_t off = (size_t)(i0 + r) * NMAT + j;
        Mout[off] = f2bf(fmaf(Q2[off], sa[r], bf2f(M0base[off])));
      }
    }
  }
}

extern "C" void kernel_launch(void* const* d_in, const int* in_sizes, int n_in,
                              void* d_out, int out_size, void* d_ws,
                              size_t ws_size, hipStream_t stream) {
  const float* A1 = (const float*)d_in[0];
  const float* A2 = (const float*)d_in[1];
  const float* N1 = (const float*)d_in[2];
  const float* N2 = (const float*)d_in[3];
  const float* H = (const float*)d_in[4];
  float* s_out = (float*)d_out;

  char* p = (char*)d_ws;
  auto take = [&](size_t bytes) {
    char* r = p;
    p += (bytes + 255) & ~(size_t)255;
    return r;
  };
  unsigned short* idx1 = (unsigned short*)take((size_t)NMAT * CAP * 2);
  unsigned short* idx2 = (unsigned short*)take((size_t)NMAT * CAP * 2);
  unsigned short* idx2T = (unsigned short*)take((size_t)CAP * NMAT * 2);
  int* cnt1 = (int*)take((size_t)NMAT * 4);
  int* cnt2 = (int*)take((size_t)NMAT * 4);
  float* N1n = (float*)take((size_t)NMAT * KATTR * 4);
  float* N2n = (float*)take((size_t)NMAT * KATTR * 4);
  float* C1 = (float*)take((size_t)NMAT * KATTR * 4);
  float* C2 = (float*)take((size_t)NMAT * KATTR * 4);
  float* Ht = (float*)take((size_t)NMAT * NMAT * 4);
  float* q = (float*)take((size_t)NMAT * NMAT * 4);
  float* Q2 = (float*)take((size_t)NMAT * NMAT * 4);
  unsigned short* Mb0 = (unsigned short*)take((size_t)NMAT * NMAT * 2);
  unsigned short* Mb1 = (unsigned short*)take((size_t)NMAT * NMAT * 2);
  unsigned short* M0b = (unsigned short*)take((size_t)NMAT * NMAT * 2);
  float* Mf = (float*)take((size_t)NMAT * NMAT * 4);
  if ((size_t)(p - (char*)d_ws) > ws_size) return;

  k_build<<<NMAT, 256, 0, stream>>>(A1, idx1, (unsigned short*)nullptr, cnt1);
  k_build<<<NMAT, 256, 0, stream>>>(A2, idx2, idx2T, cnt2);
  k_norm<<<NMAT / 4, 256, 0, stream>>>(N1, N1n);
  k_norm<<<NMAT / 4, 256, 0, stream>>>(N2, N2n);
  k_gatherN<<<NMAT, 64, 0, stream>>>(idx1, cnt1, N1n, C1);
  k_gatherN<<<NMAT, 64, 0, stream>>>(idx2, cnt2, N2n, C2);
  k_transpose<<<dim3(32, 32), 256, 0, stream>>>(H, Ht);
  k_q<<<dim3(32, 32), 256, 0, stream>>>(N1n, C1, N2n, C2, Ht, q, Q2, Mb0,
                                        M0b);
  for (int it = 0; it < NITER; ++it) {
    const unsigned short* Min = (it & 1) ? Mb1 : Mb0;
    unsigned short* Mout = (it & 1) ? Mb0 : Mb1;
    int in32 = (it == NITER - 1) ? 1 : 0;
    int out32 = (it == NITER - 2) ? 1 : 0;
    int last = (it == NITER - 1) ? 1 : 0;
    k_iter<<<NMAT / 4, 1024, 0, stream>>>(idx1, cnt1, idx2T, cnt2, Min, Mf,
                                          Q2, M0b, q, Ht, Mout, Mf, s_out,
                                          in32, out32, last);
  }
}